// Round 1
// baseline (269.813 us; speedup 1.0000x reference)
//
#include <hip/hip_runtime.h>
#include <hip/hip_bf16.h>

#define B_ROWS 65536
#define NA 128
#define D_OUT 1024
#define VBS 128
#define NCHUNK (B_ROWS / VBS)   // 512

typedef __attribute__((ext_vector_type(8))) short bf16x8s;
typedef __attribute__((ext_vector_type(4))) float f32x4;

static __device__ __forceinline__ short f2bf(float f) {
    unsigned u = __builtin_bit_cast(unsigned, f);
    u = u + 0x7FFFu + ((u >> 16) & 1u);   // round-to-nearest-even to bf16
    return (short)(u >> 16);
}

// One block per virtual batch (chunk): 128 threads, one per feature.
// Computes scale = gamma*rsqrt(var+eps), shift = beta - mean*scale, interleaved.
__global__ void gbn_stats_kernel(const float* __restrict__ a,
                                 const float* __restrict__ gamma,
                                 const float* __restrict__ beta,
                                 float* __restrict__ ss) {
    int c = blockIdx.x;
    int j = threadIdx.x;            // feature 0..127
    const float* p = a + (size_t)c * (VBS * NA) + j;
    float s = 0.f, s2 = 0.f;
#pragma unroll 8
    for (int r = 0; r < VBS; ++r) {
        float v = p[r * NA];
        s += v; s2 += v * v;
    }
    float mean = s * (1.f / VBS);
    float var  = fmaxf(s2 * (1.f / VBS) - mean * mean, 0.f);   // biased var
    float sc = gamma[j] * rsqrtf(var + 1e-5f);
    float sh = beta[j] - mean * sc;
    float2* o = (float2*)ss + (c * NA + j);
    *o = make_float2(sc, sh);
}

__global__ void wcast_kernel(const float* __restrict__ W,
                             unsigned short* __restrict__ Wb, int n) {
    int i = blockIdx.x * blockDim.x + threadIdx.x;
    if (i < n) Wb[i] = (unsigned short)f2bf(W[i]);
}

// One block per 16 output rows. 256 threads = 4 waves; wave w owns cols [w*256, w*256+256).
// GEMM (bf16 MFMA, K=128) -> *prior -> sparsemax (Michelot, matching the
// reference's tau sign: out = relu(x + tau_std)).
__global__ __launch_bounds__(256, 4) void fused_kernel(
    const float* __restrict__ a,
    const float* __restrict__ prior,
    const float* __restrict__ ss,
    const unsigned short* __restrict__ Wb,
    float* __restrict__ out) {

    const int tid  = threadIdx.x;
    const int wave = tid >> 6;        // 0..3  (N block of 256)
    const int lane = tid & 63;
    const int g    = lane >> 4;       // 0..3  (K-slice group / C row group)
    const int q    = lane & 15;       // A row / B,C col within fragment

    const int r0    = blockIdx.x * 16;
    const int chunk = r0 >> 7;

    f32x4 acc[16];
#pragma unroll
    for (int i = 0; i < 16; ++i) acc[i] = (f32x4){0.f, 0.f, 0.f, 0.f};

    const float* ssb = ss + (size_t)chunk * NA * 2;

    // ---- GEMM: C[16 x 1024] = GBN(a_tile)[16 x 128] * W^T, bf16 MFMA ----
#pragma unroll
    for (int ks = 0; ks < 4; ++ks) {
        const int k0 = ks * 32 + g * 8;
        const float4* ap = (const float4*)(a + (size_t)(r0 + q) * NA + k0);
        float4 v0 = ap[0], v1 = ap[1];
        const float4* sp = (const float4*)(ssb + k0 * 2);   // interleaved (sc,sh)
        float4 s0 = sp[0], s1 = sp[1], s2 = sp[2], s3 = sp[3];
        bf16x8s af;
        af[0] = f2bf(v0.x * s0.x + s0.y);
        af[1] = f2bf(v0.y * s0.z + s0.w);
        af[2] = f2bf(v0.z * s1.x + s1.y);
        af[3] = f2bf(v0.w * s1.z + s1.w);
        af[4] = f2bf(v1.x * s2.x + s2.y);
        af[5] = f2bf(v1.y * s2.z + s2.w);
        af[6] = f2bf(v1.z * s3.x + s3.y);
        af[7] = f2bf(v1.w * s3.z + s3.w);

        const unsigned short* wb = Wb + (size_t)(wave * 256 + q) * NA + k0;
#pragma unroll
        for (int nf = 0; nf < 16; ++nf) {
            bf16x8s bf = *(const bf16x8s*)(wb + (size_t)nf * 16 * NA);
            acc[nf] = __builtin_amdgcn_mfma_f32_16x16x32_bf16(af, bf, acc[nf], 0, 0, 0);
        }
    }

    // ---- multiply by prior (in accumulator layout) ----
    const int colbase = wave * 256 + q;
#pragma unroll
    for (int nf = 0; nf < 16; ++nf) {
        const int col = colbase + nf * 16;
#pragma unroll
        for (int r = 0; r < 4; ++r) {
            const int row = r0 + g * 4 + r;
            acc[nf][r] *= prior[(size_t)row * D_OUT + col];
        }
    }

    // ---- sparsemax threshold via Michelot fixed point ----
    __shared__ float ls[4][16][2];    // [wave][row][s,c]
    __shared__ int s_nd;

    float tau[4], cprev[4];
#pragma unroll
    for (int r = 0; r < 4; ++r) { tau[r] = -3.0e38f; cprev[r] = -1.f; }

    for (int it = 0; it < 200; ++it) {
        float s[4] = {0.f, 0.f, 0.f, 0.f};
        float c[4] = {0.f, 0.f, 0.f, 0.f};
#pragma unroll
        for (int nf = 0; nf < 16; ++nf)
#pragma unroll
            for (int r = 0; r < 4; ++r) {
                float v = acc[nf][r];
                if (v > tau[r]) { s[r] += v; c[r] += 1.f; }
            }
        // reduce over the 16 lanes (q) of each group g
#pragma unroll
        for (int m = 1; m < 16; m <<= 1) {
#pragma unroll
            for (int r = 0; r < 4; ++r) {
                s[r] += __shfl_xor(s[r], m);
                c[r] += __shfl_xor(c[r], m);
            }
        }
        if (q == 0) {
#pragma unroll
            for (int r = 0; r < 4; ++r) {
                ls[wave][g * 4 + r][0] = s[r];
                ls[wave][g * 4 + r][1] = c[r];
            }
        }
        __syncthreads();
        bool done = true;
#pragma unroll
        for (int r = 0; r < 4; ++r) {
            float S = 0.f, C = 0.f;
#pragma unroll
            for (int w2 = 0; w2 < 4; ++w2) {
                S += ls[w2][g * 4 + r][0];
                C += ls[w2][g * 4 + r][1];
            }
            tau[r] = (S - 1.f) / C;          // tau_std = (cum_k - 1)/k
            done = done && (C == cprev[r]);
            cprev[r] = C;
        }
        if (tid == 0) s_nd = 0;
        __syncthreads();
        if (!done) s_nd = 1;
        __syncthreads();
        if (s_nd == 0) break;
    }

    // ---- output: reference computes relu(x - (1-cum_k)/k) = relu(x + tau_std) ----
#pragma unroll
    for (int nf = 0; nf < 16; ++nf) {
        const int col = colbase + nf * 16;
#pragma unroll
        for (int r = 0; r < 4; ++r) {
            const int row = r0 + g * 4 + r;
            out[(size_t)row * D_OUT + col] = fmaxf(acc[nf][r] + tau[r], 0.f);
        }
    }
}

extern "C" void kernel_launch(void* const* d_in, const int* in_sizes, int n_in,
                              void* d_out, int out_size, void* d_ws, size_t ws_size,
                              hipStream_t stream) {
    const float* a     = (const float*)d_in[0];
    const float* prior = (const float*)d_in[1];
    const float* gamma = (const float*)d_in[2];
    const float* beta  = (const float*)d_in[3];
    const float* W     = (const float*)d_in[4];
    float* out = (float*)d_out;

    float* ss = (float*)d_ws;                                   // 512 KB
    unsigned short* Wb = (unsigned short*)((char*)d_ws +
                         (size_t)NCHUNK * NA * 2 * sizeof(float)); // 256 KB

    gbn_stats_kernel<<<NCHUNK, VBS, 0, stream>>>(a, gamma, beta, ss);
    wcast_kernel<<<(D_OUT * NA + 255) / 256, 256, 0, stream>>>(W, Wb, D_OUT * NA);
    fused_kernel<<<B_ROWS / 16, 256, 0, stream>>>(a, prior, ss, Wb, out);
}